// Round 1
// baseline (2310.744 us; speedup 1.0000x reference)
//
#include <hip/hip_runtime.h>
#include <hip/hip_bf16.h>

typedef __attribute__((ext_vector_type(8))) short short8x;   // 8 x bf16 (4 VGPR) MFMA A/B frag
typedef __attribute__((ext_vector_type(4))) float f32x4;     // MFMA C/D frag

__device__ __forceinline__ ushort f2bf(float f){
  unsigned int u = __builtin_bit_cast(unsigned int, f);
  u += 0x7FFFu + ((u >> 16) & 1u);          // RNE
  return (ushort)(u >> 16);
}

// ---------------- elementwise fp32 -> bf16 ----------------
__global__ __launch_bounds__(256) void cvt_kernel(const float* __restrict__ in, ushort* __restrict__ out, long n){
  long i = ((long)blockIdx.x * 256 + threadIdx.x) * 4;
  if (i >= n) return;
  float4 v = *(const float4*)(in + i);
  ushort4 o;
  o.x = f2bf(v.x); o.y = f2bf(v.y); o.z = f2bf(v.z); o.w = f2bf(v.w);
  *(ushort4*)(out + i) = o;
}

// ---- transpose-convert: in fp32 [2048][C] (row = h*128+d) -> out bf16 [16][C][128] ----
__global__ __launch_bounds__(256) void tcvt_kernel(const float* __restrict__ in, ushort* __restrict__ out, int C){
  __shared__ float t[32][33];
  const int c0 = blockIdx.x * 32, r0 = blockIdx.y * 32;
  for (int i = threadIdx.y; i < 32; i += 8)
    t[i][threadIdx.x] = in[(long)(r0 + i) * C + c0 + threadIdx.x];
  __syncthreads();
  for (int i = threadIdx.y; i < 32; i += 8){
    const int r = r0 + threadIdx.x;
    const int c = c0 + i;
    out[((long)(r >> 7) * C + c) * 128 + (r & 127)] = f2bf(t[threadIdx.x][i]);
  }
}

// ---- transpose latents bf16 [2][2048][512] -> latT [2][512][2048] ----
__global__ __launch_bounds__(256) void tlat_kernel(const ushort* __restrict__ in, ushort* __restrict__ out){
  __shared__ ushort t[32][33];
  const int c0 = blockIdx.x * 32, s0 = blockIdx.y * 32;
  const long bo = (long)blockIdx.z * 2048 * 512;
  for (int i = threadIdx.y; i < 32; i += 8)
    t[i][threadIdx.x] = in[bo + (long)(s0 + i) * 512 + c0 + threadIdx.x];
  __syncthreads();
  for (int i = threadIdx.y; i < 32; i += 8)
    out[bo + (long)(c0 + i) * 2048 + s0 + threadIdx.x] = t[threadIdx.x][i];
}

// ---------------- generic bf16 GEMM: C = A[M,K] * B  with B given as BT[N,K] ----------------
// 128x128 tile, BK=32, 4 waves (2x2), double-buffered LDS staged via global_load_lds(16B).
template<int OUTBF>
__global__ __launch_bounds__(256, 3)
void gemm_bt(const ushort* __restrict__ A, const ushort* __restrict__ BT, void* __restrict__ Cv,
             int M, int N, int K, int lda, int ldb, int ldc,
             long aZ, long bZ, long cZ, float scale)
{
  __shared__ __align__(16) ushort As[2][128 * 32];
  __shared__ __align__(16) ushort Bs[2][128 * 32];
  const int z = blockIdx.z;
  const ushort* Ab = A + (long)z * aZ;
  const ushort* Bb = BT + (long)z * bZ;
  const int tid = threadIdx.x, lane = tid & 63, w = tid >> 6;
  const int wm = w >> 1, wn = w & 1;
  const int lq = lane & 15, q4 = lane >> 4;
  const long arow = (long)blockIdx.y * 128, brow = (long)blockIdx.x * 128;
  const int lr = lane >> 2, lc = (lane & 3) * 8;   // staging: row-in-issue, col

  const f32x4 z4 = {0.f, 0.f, 0.f, 0.f};
  f32x4 acc[4][4];
#pragma unroll
  for (int i = 0; i < 4; i++)
#pragma unroll
    for (int j = 0; j < 4; j++) acc[i][j] = z4;

  auto stage = [&](int buf, int k0){
#pragma unroll
    for (int is = 0; is < 2; ++is){
      const int rb = is * 64 + w * 16;
      const ushort* ga = Ab + (arow + rb + lr) * (long)lda + k0 + lc;
      const ushort* gb = Bb + (brow + rb + lr) * (long)ldb + k0 + lc;
      __builtin_amdgcn_global_load_lds((const __attribute__((address_space(1))) void*)ga,
                                       (__attribute__((address_space(3))) void*)&As[buf][rb * 32], 16, 0, 0);
      __builtin_amdgcn_global_load_lds((const __attribute__((address_space(1))) void*)gb,
                                       (__attribute__((address_space(3))) void*)&Bs[buf][rb * 32], 16, 0, 0);
    }
  };

  const int nk = K >> 5;
  stage(0, 0);
  for (int kt = 0; kt < nk; ++kt){
    __syncthreads();
    if (kt + 1 < nk) stage((kt + 1) & 1, (kt + 1) * 32);
    const int buf = kt & 1;
    short8x a[4], b[4];
#pragma unroll
    for (int i = 0; i < 4; i++){
      a[i] = *(const short8x*)&As[buf][(wm * 64 + i * 16 + lq) * 32 + q4 * 8];
      b[i] = *(const short8x*)&Bs[buf][(wn * 64 + i * 16 + lq) * 32 + q4 * 8];
    }
#pragma unroll
    for (int i = 0; i < 4; i++)
#pragma unroll
      for (int j = 0; j < 4; j++)
        acc[i][j] = __builtin_amdgcn_mfma_f32_16x16x32_bf16(a[i], b[j], acc[i][j], 0, 0, 0);
  }

  const long crowb = arow + wm * 64;
  const long ccolb = brow + wn * 64;
#pragma unroll
  for (int i = 0; i < 4; i++)
#pragma unroll
    for (int j = 0; j < 4; j++)
#pragma unroll
      for (int r = 0; r < 4; r++){
        const long row = crowb + i * 16 + q4 * 4 + r;
        const long col = ccolb + j * 16 + lq;
        const float v = acc[i][j][r] * scale;
        if (OUTBF) ((ushort*)Cv)[(long)z * cZ + row * ldc + col] = f2bf(v);
        else       ((float*)Cv)[(long)z * cZ + row * ldc + col] = v;
      }
}

// ---------------- flash attention over latent dim, K=V=latents ----------------
// per wave: 16 q-rows; S^T = K*Q^T via MFMA (D-frag rows=t, cols=s); no-max softmax
// (scores bounded ~|2.5|); P^T frag == B-operand of PV after per-wave LDS bounce;
// O^T[c][s] accumulated 32 x f32x4; K frags read from global latents / latT (L2-hot).
__global__ __launch_bounds__(256, 2)
void flash_kernel(const ushort* __restrict__ qp, const ushort* __restrict__ lat,
                  const ushort* __restrict__ latT, ushort* __restrict__ olat)
{
  __shared__ __align__(16) ushort Pl[4][16][40];
  const int tid = threadIdx.x, lane = tid & 63, w = tid >> 6;
  const int lq = lane & 15, q4 = lane >> 4;
  const int qb = blockIdx.x, b = blockIdx.y, h = blockIdx.z;
  const int qbase = qb * 64 + w * 16;
  const long latB  = (long)b * 2048 * 512;
  const long latTB = (long)b * 512 * 2048;

  // Q fragments (reused across all t-tiles)
  short8x qf[16];
  const ushort* Qp = qp + ((long)h * 4096 + b * 2048 + qbase + lq) * 512 + q4 * 8;
#pragma unroll
  for (int kk = 0; kk < 16; kk++) qf[kk] = *(const short8x*)(Qp + kk * 32);

  const f32x4 z4 = {0.f, 0.f, 0.f, 0.f};
  f32x4 oacc[32];
#pragma unroll
  for (int i = 0; i < 32; i++) oacc[i] = z4;
  float denom = 0.f;

  const int srow = qbase + lq;             // this lane's column of S^T = query row
  const int ntw = (qbase + 16 + 31) >> 5;  // 32-wide t tiles covering t <= qbase+15
  for (int t = 0; t < ntw; ++t){
    const int t0 = t * 32;
    f32x4 st0 = z4, st1 = z4;
    const ushort* kr = lat + latB + (long)(t0 + lq) * 512 + q4 * 8;
#pragma unroll
    for (int kk = 0; kk < 16; kk++){
      short8x a0 = *(const short8x*)(kr + kk * 32);
      short8x a1 = *(const short8x*)(kr + 16 * 512 + kk * 32);
      st0 = __builtin_amdgcn_mfma_f32_16x16x32_bf16(a0, qf[kk], st0, 0, 0, 0);
      st1 = __builtin_amdgcn_mfma_f32_16x16x32_bf16(a1, qf[kk], st1, 0, 0, 0);
    }
    // mask + exp + denom
    float dsum = 0.f;
    ushort pb[8];
#pragma unroll
    for (int r = 0; r < 4; r++){
      const int tg0 = t0 + q4 * 4 + r;
      const int tg1 = tg0 + 16;
      const float p0 = (tg0 <= srow) ? __expf(st0[r]) : 0.f;
      const float p1 = (tg1 <= srow) ? __expf(st1[r]) : 0.f;
      dsum += p0 + p1;
      pb[r] = f2bf(p0); pb[4 + r] = f2bf(p1);
    }
    dsum += __shfl_xor(dsum, 16);
    dsum += __shfl_xor(dsum, 32);
    denom += dsum;
    // bounce P through per-wave LDS: write P[s=lq][tloc=half*16+q4*4+r]
    ushort4 plo, phi;
    plo.x = pb[0]; plo.y = pb[1]; plo.z = pb[2]; plo.w = pb[3];
    phi.x = pb[4]; phi.y = pb[5]; phi.z = pb[6]; phi.w = pb[7];
    *(ushort4*)&Pl[w][lq][q4 * 4]      = plo;
    *(ushort4*)&Pl[w][lq][16 + q4 * 4] = phi;
    asm volatile("s_waitcnt lgkmcnt(0)" ::: "memory");
    __builtin_amdgcn_sched_barrier(0);
    const short8x pf = *(const short8x*)&Pl[w][lq][q4 * 8];   // B-frag: P^T[t=q4*8+j][s=lq]
    // PV: O^T[c][s] += K^T[c][t] * P^T[t][s]
    const ushort* kt = latT + latTB + (long)lq * 2048 + t0 + q4 * 8;
#pragma unroll
    for (int ct = 0; ct < 32; ct++){
      short8x av = *(const short8x*)(kt + (long)ct * 16 * 2048);
      oacc[ct] = __builtin_amdgcn_mfma_f32_16x16x32_bf16(av, pf, oacc[ct], 0, 0, 0);
    }
  }

  const float inv = 1.f / denom;
  ushort* ob = olat + ((long)b * 2048 + qbase + lq) * 8192 + h * 512 + q4 * 4;
#pragma unroll
  for (int ct = 0; ct < 32; ct++){
    ushort4 o;
    o.x = f2bf(oacc[ct][0] * inv);
    o.y = f2bf(oacc[ct][1] * inv);
    o.z = f2bf(oacc[ct][2] * inv);
    o.w = f2bf(oacc[ct][3] * inv);
    *(ushort4*)(ob + ct * 16) = o;
  }
}

// ---------------- host launcher ----------------
extern "C" void kernel_launch(void* const* d_in, const int* in_sizes, int n_in,
                              void* d_out, int out_size, void* d_ws, size_t ws_size,
                              hipStream_t stream)
{
  const float* x   = (const float*)d_in[0];
  const float* Wd  = (const float*)d_in[1];
  const float* Wuk = (const float*)d_in[2];
  const float* Wuv = (const float*)d_in[3];
  const float* Wq  = (const float*)d_in[4];
  const float* Wo  = (const float*)d_in[5];
  float* out = (float*)d_out;
  ushort* ws = (ushort*)d_ws;

  ushort* xb   = ws + 0L;          // [4096][2048]
  ushort* wdb  = ws + 8388608L;    // [512][2048]
  ushort* wob  = ws + 9437184L;    // [2048][2048]
  ushort* wqt  = ws + 13631488L;   // [16][2048][128]
  ushort* wukt = ws + 17825792L;   // [16][512][128]
  ushort* wuvt = ws + 18874368L;   // [16][512][128]
  ushort* qukt = ws + 19922944L;   // [16][512][2048]
  ushort* ouvr = ws + 36700160L;   // [2048][8192]
  ushort* lat  = ws + 53477376L;   // [4096][512]
  ushort* latT = ws + 55574528L;   // [2][512][2048]
  ushort* qp   = ws + 57671680L;   // [16][4096][512]
  ushort* olat = ws + 91226112L;   // [4096][8192]

  cvt_kernel<<<8192, 256, 0, stream>>>(x,  xb,  8388608L);
  cvt_kernel<<<1024, 256, 0, stream>>>(Wd, wdb, 1048576L);
  cvt_kernel<<<4096, 256, 0, stream>>>(Wo, wob, 4194304L);
  tcvt_kernel<<<dim3(64, 64), dim3(32, 8), 0, stream>>>(Wq,  wqt,  2048);
  tcvt_kernel<<<dim3(16, 64), dim3(32, 8), 0, stream>>>(Wuk, wukt, 512);
  tcvt_kernel<<<dim3(16, 64), dim3(32, 8), 0, stream>>>(Wuv, wuvt, 512);

  // G1: q_ukT[h][c][m] = sum_d WukT[h][c][d] * WqT[h][m][d], scaled by 1/sqrt(128)
  gemm_bt<1><<<dim3(16, 4, 16), 256, 0, stream>>>(wukt, wqt, qukt, 512, 2048, 128,
      128, 128, 2048, 65536L, 262144L, 1048576L, 0.08838834764831845f);
  // G2: ouvR[m][h*512+c] = sum_d WoB[m][h*128+d] * WuvT[h][c][d]
  gemm_bt<1><<<dim3(4, 16, 16), 256, 0, stream>>>(wob, wuvt, ouvr, 2048, 512, 128,
      2048, 128, 8192, 128L, 65536L, 512L, 1.0f);
  // G3: latents = x @ Wd^T
  gemm_bt<1><<<dim3(4, 32, 1), 256, 0, stream>>>(xb, wdb, lat, 4096, 512, 2048,
      2048, 2048, 512, 0L, 0L, 0L, 1.0f);
  tlat_kernel<<<dim3(16, 64, 2), dim3(32, 8), 0, stream>>>(lat, latT);
  // G4: qp[h][(b,s)][c] = x @ q_uk[h]
  gemm_bt<1><<<dim3(4, 32, 16), 256, 0, stream>>>(xb, qukt, qp, 4096, 512, 2048,
      2048, 2048, 512, 0L, 1048576L, 2097152L, 1.0f);
  // flash causal attention over latent dim
  flash_kernel<<<dim3(32, 2, 16), 256, 0, stream>>>(qp, lat, latT, olat);
  // G5: out[(b,s)][m] = sum_{h,c} olat * ouvR   (fp32 out)
  gemm_bt<0><<<dim3(16, 32, 1), 256, 0, stream>>>(olat, ouvr, out, 4096, 2048, 8192,
      8192, 8192, 2048, 0L, 0L, 0L, 1.0f);
}

// Round 2
// 465.319 us; speedup vs baseline: 4.9659x; 4.9659x over previous
//
#include <hip/hip_runtime.h>
#include <hip/hip_bf16.h>

typedef __attribute__((ext_vector_type(8))) short short8x;   // 8 x bf16 (4 VGPR) MFMA A/B frag
typedef __attribute__((ext_vector_type(4))) float f32x4;     // MFMA C/D frag

__device__ __forceinline__ ushort f2bf(float f){
  unsigned int u = __builtin_bit_cast(unsigned int, f);
  u += 0x7FFFu + ((u >> 16) & 1u);          // RNE
  return (ushort)(u >> 16);
}

// ---------------- elementwise fp32 -> bf16 ----------------
__global__ __launch_bounds__(256) void cvt_kernel(const float* __restrict__ in, ushort* __restrict__ out, long n){
  long i = ((long)blockIdx.x * 256 + threadIdx.x) * 4;
  if (i >= n) return;
  float4 v = *(const float4*)(in + i);
  ushort4 o;
  o.x = f2bf(v.x); o.y = f2bf(v.y); o.z = f2bf(v.z); o.w = f2bf(v.w);
  *(ushort4*)(out + i) = o;
}

// ---------------- generic bf16 GEMM: C = A[M,K] * B  with B given as BT[N,K] ----------------
// 128x128 tile, BK=32, 4 waves (2x2), double-buffered LDS staged via global_load_lds(16B).
template<int OUTBF>
__global__ __launch_bounds__(256, 3)
void gemm_bt(const ushort* __restrict__ A, const ushort* __restrict__ BT, void* __restrict__ Cv,
             int M, int N, int K, int lda, int ldb, int ldc,
             long aZ, long bZ, long cZ, float scale)
{
  __shared__ __align__(16) ushort As[2][128 * 32];
  __shared__ __align__(16) ushort Bs[2][128 * 32];
  const int z = blockIdx.z;
  const ushort* Ab = A + (long)z * aZ;
  const ushort* Bb = BT + (long)z * bZ;
  const int tid = threadIdx.x, lane = tid & 63, w = tid >> 6;
  const int wm = w >> 1, wn = w & 1;
  const int lq = lane & 15, q4 = lane >> 4;
  const long arow = (long)blockIdx.y * 128, brow = (long)blockIdx.x * 128;
  const int lr = lane >> 2, lc = (lane & 3) * 8;

  const f32x4 z4 = {0.f, 0.f, 0.f, 0.f};
  f32x4 acc[4][4];
#pragma unroll
  for (int i = 0; i < 4; i++)
#pragma unroll
    for (int j = 0; j < 4; j++) acc[i][j] = z4;

  auto stage = [&](int buf, int k0){
#pragma unroll
    for (int is = 0; is < 2; ++is){
      const int rb = is * 64 + w * 16;
      const ushort* ga = Ab + (arow + rb + lr) * (long)lda + k0 + lc;
      const ushort* gb = Bb + (brow + rb + lr) * (long)ldb + k0 + lc;
      __builtin_amdgcn_global_load_lds((const __attribute__((address_space(1))) void*)ga,
                                       (__attribute__((address_space(3))) void*)&As[buf][rb * 32], 16, 0, 0);
      __builtin_amdgcn_global_load_lds((const __attribute__((address_space(1))) void*)gb,
                                       (__attribute__((address_space(3))) void*)&Bs[buf][rb * 32], 16, 0, 0);
    }
  };

  const int nk = K >> 5;
  stage(0, 0);
  for (int kt = 0; kt < nk; ++kt){
    __syncthreads();
    if (kt + 1 < nk) stage((kt + 1) & 1, (kt + 1) * 32);
    const int buf = kt & 1;
    short8x a[4], b[4];
#pragma unroll
    for (int i = 0; i < 4; i++){
      a[i] = *(const short8x*)&As[buf][(wm * 64 + i * 16 + lq) * 32 + q4 * 8];
      b[i] = *(const short8x*)&Bs[buf][(wn * 64 + i * 16 + lq) * 32 + q4 * 8];
    }
#pragma unroll
    for (int i = 0; i < 4; i++)
#pragma unroll
      for (int j = 0; j < 4; j++)
        acc[i][j] = __builtin_amdgcn_mfma_f32_16x16x32_bf16(a[i], b[j], acc[i][j], 0, 0, 0);
  }

  const long crowb = arow + wm * 64;
  const long ccolb = brow + wn * 64;
#pragma unroll
  for (int i = 0; i < 4; i++)
#pragma unroll
    for (int j = 0; j < 4; j++)
#pragma unroll
      for (int r = 0; r < 4; r++){
        const long row = crowb + i * 16 + q4 * 4 + r;
        const long col = ccolb + j * 16 + lq;
        const float v = acc[i][j][r] * scale;
        if (OUTBF) ((ushort*)Cv)[(long)z * cZ + row * ldc + col] = f2bf(v);
        else       ((float*)Cv)[(long)z * cZ + row * ldc + col] = v;
      }
}

// ---------------- flash attention, d=128, causal, per (b,h) ----------------
// 1-wave blocks, 32 q-rows per wave. S^T = K*Q^T via MFMA (4 indep chains of depth 4),
// per-wave LDS bounce of P^T, PV as O^T[d][s] += V^T[d][t] * P^T[t][s] (16 indep acc).
// Atomic LPT task grab: task t and t+1024 map to strips summing to constant work (65 tiles),
// same (b,h) for locality. No-max softmax (scores bounded ~|2.5|).
__global__ __launch_bounds__(64, 2)
void flash2_kernel(const ushort* __restrict__ q, const ushort* __restrict__ k,
                   const ushort* __restrict__ vT, ushort* __restrict__ attnO,
                   unsigned int* __restrict__ cnt)
{
  __shared__ __align__(16) ushort Pl[32][40];   // [s_local][t_local], stride 80B (16B aligned)
  const int lane = threadIdx.x;
  const int lq = lane & 15, q4 = lane >> 4;

  int tsk;
  if (lane == 0) tsk = (int)atomicAdd(cnt, 1u);
  tsk = __shfl(tsk, 0);

  const int rr_ = tsk >> 10;          // round 0: heavy strips 63..32; round 1: light 0..31
  const int u = tsk & 1023;
  const int bh = u >> 5;              // 0..31 (groups of 32 consecutive tasks share (b,h))
  const int aa = u & 31;
  const int strip = rr_ ? aa : (63 - aa);
  const int b = bh & 1, h = bh >> 1;

  const int qrow0 = strip * 32;
  const long qgbase = (long)b * 2048 + qrow0;

  // Q B-frags: qf[si][ks] covers s = qrow0+si*16+lq, d = ks*32 + q4*8 + j
  short8x qf[2][4];
#pragma unroll
  for (int si = 0; si < 2; si++){
    const ushort* qp = q + (qgbase + si * 16 + lq) * 2048 + h * 128 + q4 * 8;
#pragma unroll
    for (int ks = 0; ks < 4; ks++) qf[si][ks] = *(const short8x*)(qp + ks * 32);
  }

  const f32x4 z4 = {0.f, 0.f, 0.f, 0.f};
  f32x4 oacc[8][2];
#pragma unroll
  for (int dt = 0; dt < 8; dt++){ oacc[dt][0] = z4; oacc[dt][1] = z4; }
  float dsum0 = 0.f, dsum1 = 0.f;

  const ushort* kb_ = k + ((long)b * 2048) * 2048 + h * 128;
  const ushort* vb_ = vT + (long)h * 128 * 4096 + (long)b * 2048;

  for (int tt = 0; tt <= strip; ++tt){
    const int t0 = tt * 32;
    // K A-frags: row t = t0+ti*16+lq, k = ks*32+q4*8+j
    short8x ak[2][4];
#pragma unroll
    for (int ti = 0; ti < 2; ti++){
      const ushort* kp = kb_ + (long)(t0 + ti * 16 + lq) * 2048 + q4 * 8;
#pragma unroll
      for (int ks = 0; ks < 4; ks++) ak[ti][ks] = *(const short8x*)(kp + ks * 32);
    }
    f32x4 st[2][2] = {{z4, z4}, {z4, z4}};
#pragma unroll
    for (int ks = 0; ks < 4; ks++)
#pragma unroll
      for (int ti = 0; ti < 2; ti++)
#pragma unroll
        for (int si = 0; si < 2; si++)
          st[ti][si] = __builtin_amdgcn_mfma_f32_16x16x32_bf16(ak[ti][ks], qf[si][ks], st[ti][si], 0, 0, 0);

    // mask (diagonal tile only) + exp + partial denom, pack P^T to LDS
    const bool diag = (tt == strip);
#pragma unroll
    for (int ti = 0; ti < 2; ti++)
#pragma unroll
      for (int si = 0; si < 2; si++){
        ushort4 pb;
#pragma unroll
        for (int r = 0; r < 4; r++){
          const int tl = ti * 16 + q4 * 4 + r;
          const int sl = si * 16 + lq;
          float p = __expf(st[ti][si][r]);
          if (diag && tl > sl) p = 0.f;
          if (si) dsum1 += p; else dsum0 += p;
          ((ushort*)&pb)[r] = f2bf(p);
        }
        *(ushort4*)&Pl[si * 16 + lq][ti * 16 + q4 * 4] = pb;
      }
    asm volatile("s_waitcnt lgkmcnt(0)" ::: "memory");
    __builtin_amdgcn_sched_barrier(0);
    short8x pf0 = *(const short8x*)&Pl[lq][q4 * 8];
    short8x pf1 = *(const short8x*)&Pl[16 + lq][q4 * 8];
    __builtin_amdgcn_sched_barrier(0);
    // PV: O^T[d][s] += V^T[d][t] * P^T[t][s]
#pragma unroll
    for (int dt = 0; dt < 8; dt++){
      const short8x av = *(const short8x*)(vb_ + (long)(dt * 16 + lq) * 4096 + t0 + q4 * 8);
      oacc[dt][0] = __builtin_amdgcn_mfma_f32_16x16x32_bf16(av, pf0, oacc[dt][0], 0, 0, 0);
      oacc[dt][1] = __builtin_amdgcn_mfma_f32_16x16x32_bf16(av, pf1, oacc[dt][1], 0, 0, 0);
    }
  }

  dsum0 += __shfl_xor(dsum0, 16); dsum0 += __shfl_xor(dsum0, 32);
  dsum1 += __shfl_xor(dsum1, 16); dsum1 += __shfl_xor(dsum1, 32);
  const float inv0 = 1.f / dsum0, inv1 = 1.f / dsum1;

#pragma unroll
  for (int dt = 0; dt < 8; dt++)
#pragma unroll
    for (int si = 0; si < 2; si++){
      const float inv = si ? inv1 : inv0;
      ushort4 o;
      o.x = f2bf(oacc[dt][si][0] * inv);
      o.y = f2bf(oacc[dt][si][1] * inv);
      o.z = f2bf(oacc[dt][si][2] * inv);
      o.w = f2bf(oacc[dt][si][3] * inv);
      *(ushort4*)(attnO + (qgbase + si * 16 + lq) * 2048 + h * 128 + dt * 16 + q4 * 4) = o;
    }
}

// ---------------- host launcher ----------------
extern "C" void kernel_launch(void* const* d_in, const int* in_sizes, int n_in,
                              void* d_out, int out_size, void* d_ws, size_t ws_size,
                              hipStream_t stream)
{
  const float* x   = (const float*)d_in[0];
  const float* Wd  = (const float*)d_in[1];
  const float* Wuk = (const float*)d_in[2];
  const float* Wuv = (const float*)d_in[3];
  const float* Wq  = (const float*)d_in[4];
  const float* Wo  = (const float*)d_in[5];
  float* out = (float*)d_out;
  ushort* ws = (ushort*)d_ws;

  ushort* xb    = ws + 0L;          // [4096][2048]
  ushort* wdb   = ws + 8388608L;    // [512][2048]
  ushort* wqb   = ws + 9437184L;    // [2048(h,d)][2048(m)]
  ushort* wob   = ws + 13631488L;   // [2048(m)][2048(h,d)]
  ushort* wukb  = ws + 17825792L;   // [2048(h,d)][512(c)]
  ushort* wuvb  = ws + 18874368L;   // [2048(h,d)][512(c)]
  ushort* lat   = ws + 19922944L;   // [4096(b,t)][512(c)]
  ushort* qb    = ws + 22020096L;   // [4096(b,s)][2048(h,d)]
  ushort* kb    = ws + 30408704L;   // [4096(b,t)][2048(h,d)]
  ushort* vTb   = ws + 38797312L;   // [2048(h,d)][4096(b,t)]
  ushort* attnO = ws + 47185920L;   // [4096(b,s)][2048(h,d)]
  unsigned int* cnt = (unsigned int*)(ws + 55574528L);

  cvt_kernel<<<8192, 256, 0, stream>>>(x,   xb,   8388608L);
  cvt_kernel<<<1024, 256, 0, stream>>>(Wd,  wdb,  1048576L);
  cvt_kernel<<<4096, 256, 0, stream>>>(Wq,  wqb,  4194304L);
  cvt_kernel<<<4096, 256, 0, stream>>>(Wo,  wob,  4194304L);
  cvt_kernel<<<1024, 256, 0, stream>>>(Wuk, wukb, 1048576L);
  cvt_kernel<<<1024, 256, 0, stream>>>(Wuv, wuvb, 1048576L);
  hipMemsetAsync(cnt, 0, 4, stream);

  // latents = x @ Wd^T : [4096, 512]
  gemm_bt<1><<<dim3(4, 32, 1), 256, 0, stream>>>(xb, wdb, lat, 4096, 512, 2048,
      2048, 2048, 512, 0L, 0L, 0L, 1.0f);
  // q = (x @ Wq^T) / sqrt(128) : [4096, 2048]
  gemm_bt<1><<<dim3(16, 32, 1), 256, 0, stream>>>(xb, wqb, qb, 4096, 2048, 2048,
      2048, 2048, 2048, 0L, 0L, 0L, 0.08838834764831845f);
  // k = lat @ Wuk^T : [4096, 2048]
  gemm_bt<1><<<dim3(16, 32, 1), 256, 0, stream>>>(lat, wukb, kb, 4096, 2048, 512,
      512, 512, 2048, 0L, 0L, 0L, 1.0f);
  // vT = Wuv @ lat^T : [2048(h,d)][4096(b,t)]
  gemm_bt<1><<<dim3(32, 16, 1), 256, 0, stream>>>(wuvb, lat, vTb, 2048, 4096, 512,
      512, 512, 4096, 0L, 0L, 0L, 1.0f);
  // flash attention (causal, d=128): attnO [4096][2048]
  flash2_kernel<<<2048, 64, 0, stream>>>(qb, kb, vTb, attnO, cnt);
  // out = attnO @ Wo^T : fp32 [4096, 2048]
  gemm_bt<0><<<dim3(16, 32, 1), 256, 0, stream>>>(attnO, wob, out, 4096, 2048, 2048,
      2048, 2048, 2048, 0L, 0L, 0L, 1.0f);
}

// Round 3
// 293.642 us; speedup vs baseline: 7.8693x; 1.5846x over previous
//
#include <hip/hip_runtime.h>
#include <hip/hip_bf16.h>

typedef __attribute__((ext_vector_type(8))) short short8x;   // 8 x bf16 (4 VGPR) MFMA A/B frag
typedef __attribute__((ext_vector_type(4))) float f32x4;     // MFMA C/D frag

__device__ __forceinline__ ushort f2bf(float f){
  unsigned int u = __builtin_bit_cast(unsigned int, f);
  u += 0x7FFFu + ((u >> 16) & 1u);          // RNE
  return (ushort)(u >> 16);
}

// ---------------- elementwise fp32 -> bf16 ----------------
__global__ __launch_bounds__(256) void cvt_kernel(const float* __restrict__ in, ushort* __restrict__ out, long n){
  long i = ((long)blockIdx.x * 256 + threadIdx.x) * 4;
  if (i >= n) return;
  float4 v = *(const float4*)(in + i);
  ushort4 o;
  o.x = f2bf(v.x); o.y = f2bf(v.y); o.z = f2bf(v.z); o.w = f2bf(v.w);
  *(ushort4*)(out + i) = o;
}

// ---------------- generic bf16 GEMM: C = A[M,K] * B  with B given as BT[N,K] ----------------
// 128x128 tile, BK=32, 4 waves (2x2), double-buffered LDS staged via global_load_lds(16B).
// XCD-aware block swizzle (T1): all launches have (gridDim.x*gridDim.y) % 8 == 0.
template<int OUTBF>
__global__ __launch_bounds__(256, 3)
void gemm_bt(const ushort* __restrict__ A, const ushort* __restrict__ BT, void* __restrict__ Cv,
             int M, int N, int K, int lda, int ldb, int ldc,
             long aZ, long bZ, long cZ, float scale)
{
  __shared__ __align__(16) ushort As[2][128 * 32];
  __shared__ __align__(16) ushort Bs[2][128 * 32];
  const int z = blockIdx.z;
  const ushort* Ab = A + (long)z * aZ;
  const ushort* Bb = BT + (long)z * bZ;
  const int tid = threadIdx.x, lane = tid & 63, w = tid >> 6;
  const int wm = w >> 1, wn = w & 1;
  const int lq = lane & 15, q4 = lane >> 4;

  int lin = blockIdx.x + gridDim.x * blockIdx.y;
  const int cpx = (gridDim.x * gridDim.y) >> 3;
  lin = (lin & 7) * cpx + (lin >> 3);
  const int bx = lin % gridDim.x, by = lin / gridDim.x;

  const long arow = (long)by * 128, brow = (long)bx * 128;
  const int lr = lane >> 2, lc = (lane & 3) * 8;

  const f32x4 z4 = {0.f, 0.f, 0.f, 0.f};
  f32x4 acc[4][4];
#pragma unroll
  for (int i = 0; i < 4; i++)
#pragma unroll
    for (int j = 0; j < 4; j++) acc[i][j] = z4;

  auto stage = [&](int buf, int k0){
#pragma unroll
    for (int is = 0; is < 2; ++is){
      const int rb = is * 64 + w * 16;
      const ushort* ga = Ab + (arow + rb + lr) * (long)lda + k0 + lc;
      const ushort* gb = Bb + (brow + rb + lr) * (long)ldb + k0 + lc;
      __builtin_amdgcn_global_load_lds((const __attribute__((address_space(1))) void*)ga,
                                       (__attribute__((address_space(3))) void*)&As[buf][rb * 32], 16, 0, 0);
      __builtin_amdgcn_global_load_lds((const __attribute__((address_space(1))) void*)gb,
                                       (__attribute__((address_space(3))) void*)&Bs[buf][rb * 32], 16, 0, 0);
    }
  };

  const int nk = K >> 5;
  stage(0, 0);
  for (int kt = 0; kt < nk; ++kt){
    __syncthreads();
    if (kt + 1 < nk) stage((kt + 1) & 1, (kt + 1) * 32);
    const int buf = kt & 1;
    short8x a[4], b[4];
#pragma unroll
    for (int i = 0; i < 4; i++){
      a[i] = *(const short8x*)&As[buf][(wm * 64 + i * 16 + lq) * 32 + q4 * 8];
      b[i] = *(const short8x*)&Bs[buf][(wn * 64 + i * 16 + lq) * 32 + q4 * 8];
    }
#pragma unroll
    for (int i = 0; i < 4; i++)
#pragma unroll
      for (int j = 0; j < 4; j++)
        acc[i][j] = __builtin_amdgcn_mfma_f32_16x16x32_bf16(a[i], b[j], acc[i][j], 0, 0, 0);
  }

  const long crowb = arow + wm * 64;
  const long ccolb = brow + wn * 64;
#pragma unroll
  for (int i = 0; i < 4; i++)
#pragma unroll
    for (int j = 0; j < 4; j++)
#pragma unroll
      for (int r = 0; r < 4; r++){
        const long row = crowb + i * 16 + q4 * 4 + r;
        const long col = ccolb + j * 16 + lq;
        const float v = acc[i][j][r] * scale;
        if (OUTBF) ((ushort*)Cv)[(long)z * cZ + row * ldc + col] = f2bf(v);
        else       ((float*)Cv)[(long)z * cZ + row * ldc + col] = v;
      }
}

// ---------------- flash attention v3: d=128, causal, LDS-staged K/V, 2-phase pipeline ----------
// 4-wave blocks; wave w owns q-rows [sblk*128+32w, +32); all waves share (b,h) so K/V tiles are
// staged cooperatively once per block (double-buffered, global_load_lds 16B, prefetch 1 ahead).
// K-tile reads use granule^=(row&7) XOR swizzle (pre-swizzled global source, swizzled ds_read).
// V^T-tile reads are contiguous-1KB per instr (conflict-free, no swizzle).
// S^T = K*Q^T MFMA; per-wave LDS P-bounce; O^T[d][s] accumulation. Atomic LPT task grab.
__global__ __launch_bounds__(256, 2)
void flash3_kernel(const ushort* __restrict__ q, const ushort* __restrict__ k,
                   const ushort* __restrict__ vT, ushort* __restrict__ attnO,
                   unsigned int* __restrict__ cnt)
{
  __shared__ __align__(16) ushort Kb[2][32 * 128];   // [t][d] swizzled granules, 8KB each
  __shared__ __align__(16) ushort Vb[2][128 * 32];   // [d][t] linear, 8KB each
  __shared__ __align__(16) ushort Pl[4][32][40];     // per-wave P^T bounce
  __shared__ int tsk_s;

  const int tid = threadIdx.x, lane = tid & 63, w = tid >> 6;
  const int lq = lane & 15, q4 = lane >> 4;

  if (tid == 0) tsk_s = (int)atomicAdd(cnt, 1u);
  __syncthreads();
  const int tsk = tsk_s;
  const int bh = tsk & 31;
  const int g8 = (tsk >> 5) & 15;
  const int sblk = (tsk < 256) ? (15 - g8) : (g8 - 8);   // heavy strips grabbed first
  const int b = bh & 1, h = bh >> 1;

  const int qrow0 = sblk * 128 + w * 32;
  const long qgbase = (long)b * 2048 + qrow0;
  const int nt = sblk * 4 + 4;          // tiles staged by this block
  const int wmax = sblk * 4 + w;        // wave computes tt <= wmax; diagonal at tt == wmax

  // Q B-frags (reused all tiles): s = qrow0+si*16+lq, d = ks*32+q4*8+j
  short8x qf[2][4];
#pragma unroll
  for (int si = 0; si < 2; si++){
    const ushort* qp = q + (qgbase + si * 16 + lq) * 2048 + h * 128 + q4 * 8;
#pragma unroll
    for (int ks = 0; ks < 4; ks++) qf[si][ks] = *(const short8x*)(qp + ks * 32);
  }

  const f32x4 z4 = {0.f, 0.f, 0.f, 0.f};
  f32x4 oacc[8][2];
#pragma unroll
  for (int dt = 0; dt < 8; dt++){ oacc[dt][0] = z4; oacc[dt][1] = z4; }
  float dsum0 = 0.f, dsum1 = 0.f;

  const ushort* kb_ = k + (long)b * 2048 * 2048 + h * 128;       // row t stride 2048 elems
  const ushort* vb_ = vT + (long)h * 128 * 4096 + (long)b * 2048; // row d stride 4096 elems

  auto stage = [&](int buf, int tt){
    const int t0 = tt * 32;
#pragma unroll
    for (int is = 0; is < 2; ++is){
      const int ofse = is * 2048 + w * 512;            // wave-uniform LDS elem offset
      // K: linear LDS granule g holds global granule g^(row&7)  (rows of 128 elems)
      {
        const int row = (ofse >> 7) + (lane >> 4);     // 0..31
        const int gsw = (lane & 15) ^ (row & 7);
        const ushort* gk = kb_ + (long)(t0 + row) * 2048 + gsw * 8;
        __builtin_amdgcn_global_load_lds((const __attribute__((address_space(1))) void*)gk,
            (__attribute__((address_space(3))) void*)&Kb[buf][ofse], 16, 0, 0);
      }
      // V^T: linear [d][32 t] rows of 64B
      {
        const int drow = (ofse >> 5) + (lane >> 2);    // 0..127
        const ushort* gv = vb_ + (long)drow * 4096 + t0 + (lane & 3) * 8;
        __builtin_amdgcn_global_load_lds((const __attribute__((address_space(1))) void*)gv,
            (__attribute__((address_space(3))) void*)&Vb[buf][ofse], 16, 0, 0);
      }
    }
  };

  stage(0, 0);
  asm volatile("s_waitcnt vmcnt(0)" ::: "memory");
  __syncthreads();

  for (int tt = 0; tt < nt; ++tt){
    const int cur = tt & 1;
    if (tt + 1 < nt) stage(cur ^ 1, tt + 1);

    if (tt <= wmax){
      // K A-frags from swizzled LDS: row r = ti*16+lq, granule (ks*4+q4)^(r&7)
      short8x ak[2][4];
#pragma unroll
      for (int ti = 0; ti < 2; ti++){
        const int r = ti * 16 + lq;
        const int rb = r * 128;
        const int rx = r & 7;
#pragma unroll
        for (int ks = 0; ks < 4; ks++)
          ak[ti][ks] = *(const short8x*)&Kb[cur][rb + (((ks * 4 + q4) ^ rx) * 8)];
      }
      f32x4 st[2][2] = {{z4, z4}, {z4, z4}};
#pragma unroll
      for (int ks = 0; ks < 4; ks++)
#pragma unroll
        for (int ti = 0; ti < 2; ti++)
#pragma unroll
          for (int si = 0; si < 2; si++)
            st[ti][si] = __builtin_amdgcn_mfma_f32_16x16x32_bf16(ak[ti][ks], qf[si][ks], st[ti][si], 0, 0, 0);

      const bool diag = (tt == wmax);
#pragma unroll
      for (int ti = 0; ti < 2; ti++)
#pragma unroll
        for (int si = 0; si < 2; si++){
          ushort4 pb;
#pragma unroll
          for (int r = 0; r < 4; r++){
            const int tl = ti * 16 + q4 * 4 + r;
            const int sl = si * 16 + lq;
            float p = __expf(st[ti][si][r]);
            if (diag && tl > sl) p = 0.f;
            if (si) dsum1 += p; else dsum0 += p;
            ((ushort*)&pb)[r] = f2bf(p);
          }
          *(ushort4*)&Pl[w][si * 16 + lq][ti * 16 + q4 * 4] = pb;
        }
      asm volatile("s_waitcnt lgkmcnt(0)" ::: "memory");
      __builtin_amdgcn_sched_barrier(0);
      short8x pf0 = *(const short8x*)&Pl[w][lq][q4 * 8];
      short8x pf1 = *(const short8x*)&Pl[w][16 + lq][q4 * 8];
      __builtin_amdgcn_sched_barrier(0);
      // PV: O^T[d][s] += V^T[d][t] * P^T[t][s]; V frag read is a contiguous 1KB per dt
#pragma unroll
      for (int dt = 0; dt < 8; dt++){
        const short8x av = *(const short8x*)&Vb[cur][(dt * 16 + lq) * 32 + q4 * 8];
        oacc[dt][0] = __builtin_amdgcn_mfma_f32_16x16x32_bf16(av, pf0, oacc[dt][0], 0, 0, 0);
        oacc[dt][1] = __builtin_amdgcn_mfma_f32_16x16x32_bf16(av, pf1, oacc[dt][1], 0, 0, 0);
      }
    }
    asm volatile("s_waitcnt vmcnt(0)" ::: "memory");
    __syncthreads();
  }

  dsum0 += __shfl_xor(dsum0, 16); dsum0 += __shfl_xor(dsum0, 32);
  dsum1 += __shfl_xor(dsum1, 16); dsum1 += __shfl_xor(dsum1, 32);
  const float inv0 = 1.f / dsum0, inv1 = 1.f / dsum1;

#pragma unroll
  for (int dt = 0; dt < 8; dt++)
#pragma unroll
    for (int si = 0; si < 2; si++){
      const float inv = si ? inv1 : inv0;
      ushort4 o;
      o.x = f2bf(oacc[dt][si][0] * inv);
      o.y = f2bf(oacc[dt][si][1] * inv);
      o.z = f2bf(oacc[dt][si][2] * inv);
      o.w = f2bf(oacc[dt][si][3] * inv);
      *(ushort4*)(attnO + (qgbase + si * 16 + lq) * 2048 + h * 128 + dt * 16 + q4 * 4) = o;
    }
}

// ---------------- host launcher ----------------
extern "C" void kernel_launch(void* const* d_in, const int* in_sizes, int n_in,
                              void* d_out, int out_size, void* d_ws, size_t ws_size,
                              hipStream_t stream)
{
  const float* x   = (const float*)d_in[0];
  const float* Wd  = (const float*)d_in[1];
  const float* Wuk = (const float*)d_in[2];
  const float* Wuv = (const float*)d_in[3];
  const float* Wq  = (const float*)d_in[4];
  const float* Wo  = (const float*)d_in[5];
  float* out = (float*)d_out;
  ushort* ws = (ushort*)d_ws;

  ushort* xb    = ws + 0L;          // [4096][2048]
  ushort* wdb   = ws + 8388608L;    // [512][2048]
  ushort* wqb   = ws + 9437184L;    // [2048(h,d)][2048(m)]
  ushort* wob   = ws + 13631488L;   // [2048(m)][2048(h,d)]
  ushort* wukb  = ws + 17825792L;   // [2048(h,d)][512(c)]
  ushort* wuvb  = ws + 18874368L;   // [2048(h,d)][512(c)]
  ushort* lat   = ws + 19922944L;   // [4096(b,t)][512(c)]
  ushort* qb    = ws + 22020096L;   // [4096(b,s)][2048(h,d)]
  ushort* kb    = ws + 30408704L;   // [4096(b,t)][2048(h,d)]
  ushort* vTb   = ws + 38797312L;   // [2048(h,d)][4096(b,t)]
  ushort* attnO = ws + 47185920L;   // [4096(b,s)][2048(h,d)]
  unsigned int* cnt = (unsigned int*)(ws + 55574528L);

  cvt_kernel<<<8192, 256, 0, stream>>>(x,   xb,   8388608L);
  cvt_kernel<<<1024, 256, 0, stream>>>(Wd,  wdb,  1048576L);
  cvt_kernel<<<4096, 256, 0, stream>>>(Wq,  wqb,  4194304L);
  cvt_kernel<<<4096, 256, 0, stream>>>(Wo,  wob,  4194304L);
  cvt_kernel<<<1024, 256, 0, stream>>>(Wuk, wukb, 1048576L);
  cvt_kernel<<<1024, 256, 0, stream>>>(Wuv, wuvb, 1048576L);
  hipMemsetAsync(cnt, 0, 4, stream);

  // latents = x @ Wd^T : [4096, 512]
  gemm_bt<1><<<dim3(4, 32, 1), 256, 0, stream>>>(xb, wdb, lat, 4096, 512, 2048,
      2048, 2048, 512, 0L, 0L, 0L, 1.0f);
  // q = (x @ Wq^T) / sqrt(128) : [4096, 2048]
  gemm_bt<1><<<dim3(16, 32, 1), 256, 0, stream>>>(xb, wqb, qb, 4096, 2048, 2048,
      2048, 2048, 2048, 0L, 0L, 0L, 0.08838834764831845f);
  // k = lat @ Wuk^T : [4096, 2048]
  gemm_bt<1><<<dim3(16, 32, 1), 256, 0, stream>>>(lat, wukb, kb, 4096, 2048, 512,
      512, 512, 2048, 0L, 0L, 0L, 1.0f);
  // vT = Wuv @ lat^T : [2048(h,d)][4096(b,t)]
  gemm_bt<1><<<dim3(32, 16, 1), 256, 0, stream>>>(wuvb, lat, vTb, 2048, 4096, 512,
      512, 512, 4096, 0L, 0L, 0L, 1.0f);
  // flash attention (causal, d=128): attnO [4096][2048]
  flash3_kernel<<<512, 256, 0, stream>>>(qb, kb, vTb, attnO, cnt);
  // out = attnO @ Wo^T : fp32 [4096, 2048]
  gemm_bt<0><<<dim3(16, 32, 1), 256, 0, stream>>>(attnO, wob, out, 4096, 2048, 2048,
      2048, 2048, 2048, 0L, 0L, 0L, 1.0f);
}

// Round 4
// 283.217 us; speedup vs baseline: 8.1589x; 1.0368x over previous
//
#include <hip/hip_runtime.h>
#include <hip/hip_bf16.h>

typedef __attribute__((ext_vector_type(8))) short short8x;   // 8 x bf16 (4 VGPR) MFMA A/B frag
typedef __attribute__((ext_vector_type(4))) float f32x4;     // MFMA C/D frag

__device__ __forceinline__ ushort f2bf(float f){
  union { __hip_bfloat16 b; ushort u; } cvt;
  cvt.b = __float2bfloat16(f);                // RNE; compiler can pair into v_cvt_pk_bf16_f32
  return cvt.u;
}

// ---------------- elementwise fp32 -> bf16 ----------------
__global__ __launch_bounds__(256) void cvt_kernel(const float* __restrict__ in, ushort* __restrict__ out, long n){
  long i = ((long)blockIdx.x * 256 + threadIdx.x) * 4;
  if (i >= n) return;
  float4 v = *(const float4*)(in + i);
  ushort4 o;
  o.x = f2bf(v.x); o.y = f2bf(v.y); o.z = f2bf(v.z); o.w = f2bf(v.w);
  *(ushort4*)(out + i) = o;
}

// ---------------- generic bf16 GEMM: C = A[M,K] * B  with B given as BT[N,K] ----------------
// 128x128 tile, BK=32, 4 waves (2x2), double-buffered LDS staged via global_load_lds(16B).
// XCD-aware block swizzle (T1): all launches have (gridDim.x*gridDim.y) % 8 == 0.
template<int OUTBF>
__global__ __launch_bounds__(256, 3)
void gemm_bt(const ushort* __restrict__ A, const ushort* __restrict__ BT, void* __restrict__ Cv,
             int M, int N, int K, int lda, int ldb, int ldc,
             long aZ, long bZ, long cZ, float scale)
{
  __shared__ __align__(16) ushort As[2][128 * 32];
  __shared__ __align__(16) ushort Bs[2][128 * 32];
  const int z = blockIdx.z;
  const ushort* Ab = A + (long)z * aZ;
  const ushort* Bb = BT + (long)z * bZ;
  const int tid = threadIdx.x, lane = tid & 63, w = tid >> 6;
  const int wm = w >> 1, wn = w & 1;
  const int lq = lane & 15, q4 = lane >> 4;

  int lin = blockIdx.x + gridDim.x * blockIdx.y;
  const int cpx = (gridDim.x * gridDim.y) >> 3;
  lin = (lin & 7) * cpx + (lin >> 3);
  const int bx = lin % gridDim.x, by = lin / gridDim.x;

  const long arow = (long)by * 128, brow = (long)bx * 128;
  const int lr = lane >> 2, lc = (lane & 3) * 8;

  const f32x4 z4 = {0.f, 0.f, 0.f, 0.f};
  f32x4 acc[4][4];
#pragma unroll
  for (int i = 0; i < 4; i++)
#pragma unroll
    for (int j = 0; j < 4; j++) acc[i][j] = z4;

  auto stage = [&](int buf, int k0){
#pragma unroll
    for (int is = 0; is < 2; ++is){
      const int rb = is * 64 + w * 16;
      const ushort* ga = Ab + (arow + rb + lr) * (long)lda + k0 + lc;
      const ushort* gb = Bb + (brow + rb + lr) * (long)ldb + k0 + lc;
      __builtin_amdgcn_global_load_lds((const __attribute__((address_space(1))) void*)ga,
                                       (__attribute__((address_space(3))) void*)&As[buf][rb * 32], 16, 0, 0);
      __builtin_amdgcn_global_load_lds((const __attribute__((address_space(1))) void*)gb,
                                       (__attribute__((address_space(3))) void*)&Bs[buf][rb * 32], 16, 0, 0);
    }
  };

  const int nk = K >> 5;
  stage(0, 0);
  for (int kt = 0; kt < nk; ++kt){
    __syncthreads();
    if (kt + 1 < nk) stage((kt + 1) & 1, (kt + 1) * 32);
    const int buf = kt & 1;
    short8x a[4], b[4];
#pragma unroll
    for (int i = 0; i < 4; i++){
      a[i] = *(const short8x*)&As[buf][(wm * 64 + i * 16 + lq) * 32 + q4 * 8];
      b[i] = *(const short8x*)&Bs[buf][(wn * 64 + i * 16 + lq) * 32 + q4 * 8];
    }
#pragma unroll
    for (int i = 0; i < 4; i++)
#pragma unroll
      for (int j = 0; j < 4; j++)
        acc[i][j] = __builtin_amdgcn_mfma_f32_16x16x32_bf16(a[i], b[j], acc[i][j], 0, 0, 0);
  }

  const long crowb = arow + wm * 64;
  const long ccolb = brow + wn * 64;
#pragma unroll
  for (int i = 0; i < 4; i++)
#pragma unroll
    for (int j = 0; j < 4; j++)
#pragma unroll
      for (int r = 0; r < 4; r++){
        const long row = crowb + i * 16 + q4 * 4 + r;
        const long col = ccolb + j * 16 + lq;
        const float v = acc[i][j][r] * scale;
        if (OUTBF) ((ushort*)Cv)[(long)z * cZ + row * ldc + col] = f2bf(v);
        else       ((float*)Cv)[(long)z * cZ + row * ldc + col] = v;
      }
}

// ---------------- flash attention v4: d=128, causal, constant-work paired strips ------------
// 256 blocks (one per CU), 4 waves each. Block blkid handles (b,h) = blkid>>3 and the
// antithetic strip pair {S, 15-S} (S = blkid&7) sequentially: staged tiles
// (4S+4) + (64-4S) = 68 for EVERY block -> perfectly balanced static schedule.
// Depth-2 pipeline with counted vmcnt(4): stage(tt+2) after barrier-B, never drain mid-loop.
// K-tile LDS granule^=(row&7) swizzle (pre-swizzled global src + swizzled read, rule #21).
__global__ __launch_bounds__(256, 1)
void flash4_kernel(const ushort* __restrict__ q, const ushort* __restrict__ k,
                   const ushort* __restrict__ vT, ushort* __restrict__ attnO)
{
  __shared__ __align__(16) ushort Kb[2][32 * 128];   // [t][d] swizzled granules, 8KB each
  __shared__ __align__(16) ushort Vb[2][128 * 32];   // [d][t] linear, 8KB each
  __shared__ __align__(16) ushort Pl[4][32][40];     // per-wave P^T bounce

  const int tid = threadIdx.x, lane = tid & 63, w = tid >> 6;
  const int lq = lane & 15, q4 = lane >> 4;

  const int bh = blockIdx.x >> 3;
  const int S  = blockIdx.x & 7;
  const int b = bh & 1, h = bh >> 1;

  const ushort* kb_ = k + (long)b * 2048 * 2048 + h * 128;        // row t stride 2048 elems
  const ushort* vb_ = vT + (long)h * 128 * 4096 + (long)b * 2048; // row d stride 4096 elems

  auto stage = [&](int buf, int tt){
    const int t0 = tt * 32;
#pragma unroll
    for (int is = 0; is < 2; ++is){
      const int ofse = is * 2048 + w * 512;            // wave-uniform LDS elem offset
      {
        const int row = (ofse >> 7) + (lane >> 4);     // 0..31
        const int gsw = (lane & 15) ^ (row & 7);
        const ushort* gk = kb_ + (long)(t0 + row) * 2048 + gsw * 8;
        __builtin_amdgcn_global_load_lds((const __attribute__((address_space(1))) void*)gk,
            (__attribute__((address_space(3))) void*)&Kb[buf][ofse], 16, 0, 0);
      }
      {
        const int drow = (ofse >> 5) + (lane >> 2);    // 0..127
        const ushort* gv = vb_ + (long)drow * 4096 + t0 + (lane & 3) * 8;
        __builtin_amdgcn_global_load_lds((const __attribute__((address_space(1))) void*)gv,
            (__attribute__((address_space(3))) void*)&Vb[buf][ofse], 16, 0, 0);
      }
    }
  };

  const f32x4 z4 = {0.f, 0.f, 0.f, 0.f};

#pragma unroll 1
  for (int pass = 0; pass < 2; ++pass){
    const int strip = pass ? (15 - S) : S;
    const int nt    = pass ? (64 - 4 * S) : (4 * S + 4);
    const int wdiag = pass ? (60 - 4 * S + w) : (4 * S + w);

    const int qrow0 = strip * 128 + w * 32;
    const long qgbase = (long)b * 2048 + qrow0;

    // Q B-frags (reused all tiles): s = qrow0+si*16+lq, d = ks*32+q4*8+j
    short8x qf[2][4];
#pragma unroll
    for (int si = 0; si < 2; si++){
      const ushort* qp = q + (qgbase + si * 16 + lq) * 2048 + h * 128 + q4 * 8;
#pragma unroll
      for (int ks = 0; ks < 4; ks++) qf[si][ks] = *(const short8x*)(qp + ks * 32);
    }

    f32x4 oacc[8][2];
#pragma unroll
    for (int dt = 0; dt < 8; dt++){ oacc[dt][0] = z4; oacc[dt][1] = z4; }
    float dsum0 = 0.f, dsum1 = 0.f;

    stage(0, 0);
    stage(1, 1);          // nt >= 4 always

#pragma unroll 1
    for (int tt = 0; tt < nt; ++tt){
      if (tt == nt - 1) asm volatile("s_waitcnt vmcnt(0)" ::: "memory");
      else              asm volatile("s_waitcnt vmcnt(4)" ::: "memory");
      __syncthreads();
      const int cur = tt & 1;

      if (tt <= wdiag){
        // K A-frags from swizzled LDS: row r = ti*16+lq, granule (ks*4+q4)^(r&7)
        short8x ak[2][4];
#pragma unroll
        for (int ti = 0; ti < 2; ti++){
          const int r = ti * 16 + lq;
          const int rb = r * 128;
          const int rx = r & 7;
#pragma unroll
          for (int ks = 0; ks < 4; ks++)
            ak[ti][ks] = *(const short8x*)&Kb[cur][rb + (((ks * 4 + q4) ^ rx) * 8)];
        }
        f32x4 st[2][2] = {{z4, z4}, {z4, z4}};
#pragma unroll
        for (int ks = 0; ks < 4; ks++)
#pragma unroll
          for (int ti = 0; ti < 2; ti++)
#pragma unroll
            for (int si = 0; si < 2; si++)
              st[ti][si] = __builtin_amdgcn_mfma_f32_16x16x32_bf16(ak[ti][ks], qf[si][ks], st[ti][si], 0, 0, 0);

        const bool diag = (tt == wdiag);
#pragma unroll
        for (int ti = 0; ti < 2; ti++)
#pragma unroll
          for (int si = 0; si < 2; si++){
            ushort4 pb;
#pragma unroll
            for (int r = 0; r < 4; r++){
              const int tl = ti * 16 + q4 * 4 + r;
              const int sl = si * 16 + lq;
              float p = __expf(st[ti][si][r]);
              if (diag && tl > sl) p = 0.f;
              if (si) dsum1 += p; else dsum0 += p;
              ((ushort*)&pb)[r] = f2bf(p);
            }
            *(ushort4*)&Pl[w][si * 16 + lq][ti * 16 + q4 * 4] = pb;
          }
        asm volatile("s_waitcnt lgkmcnt(0)" ::: "memory");
        __builtin_amdgcn_sched_barrier(0);
        short8x pf0 = *(const short8x*)&Pl[w][lq][q4 * 8];
        short8x pf1 = *(const short8x*)&Pl[w][16 + lq][q4 * 8];
        __builtin_amdgcn_sched_barrier(0);
        // PV: O^T[d][s] += V^T[d][t] * P^T[t][s]; V frag read is contiguous 1KB per dt
#pragma unroll
        for (int dt = 0; dt < 8; dt++){
          const short8x av = *(const short8x*)&Vb[cur][(dt * 16 + lq) * 32 + q4 * 8];
          oacc[dt][0] = __builtin_amdgcn_mfma_f32_16x16x32_bf16(av, pf0, oacc[dt][0], 0, 0, 0);
          oacc[dt][1] = __builtin_amdgcn_mfma_f32_16x16x32_bf16(av, pf1, oacc[dt][1], 0, 0, 0);
        }
      }
      __syncthreads();                        // all reads of buf[cur] complete
      if (tt + 2 < nt) stage(cur, tt + 2);    // overwrite buf[cur] = buf[(tt+2)&1]
    }

    dsum0 += __shfl_xor(dsum0, 16); dsum0 += __shfl_xor(dsum0, 32);
    dsum1 += __shfl_xor(dsum1, 16); dsum1 += __shfl_xor(dsum1, 32);
    const float inv0 = 1.f / dsum0, inv1 = 1.f / dsum1;

#pragma unroll
    for (int dt = 0; dt < 8; dt++)
#pragma unroll
      for (int si = 0; si < 2; si++){
        const float inv = si ? inv1 : inv0;
        ushort4 o;
        o.x = f2bf(oacc[dt][si][0] * inv);
        o.y = f2bf(oacc[dt][si][1] * inv);
        o.z = f2bf(oacc[dt][si][2] * inv);
        o.w = f2bf(oacc[dt][si][3] * inv);
        *(ushort4*)(attnO + (qgbase + si * 16 + lq) * 2048 + h * 128 + dt * 16 + q4 * 4) = o;
      }
  }
}

// ---------------- host launcher ----------------
extern "C" void kernel_launch(void* const* d_in, const int* in_sizes, int n_in,
                              void* d_out, int out_size, void* d_ws, size_t ws_size,
                              hipStream_t stream)
{
  const float* x   = (const float*)d_in[0];
  const float* Wd  = (const float*)d_in[1];
  const float* Wuk = (const float*)d_in[2];
  const float* Wuv = (const float*)d_in[3];
  const float* Wq  = (const float*)d_in[4];
  const float* Wo  = (const float*)d_in[5];
  float* out = (float*)d_out;
  ushort* ws = (ushort*)d_ws;

  ushort* xb    = ws + 0L;          // [4096][2048]
  ushort* wdb   = ws + 8388608L;    // [512][2048]
  ushort* wqb   = ws + 9437184L;    // [2048(h,d)][2048(m)]
  ushort* wob   = ws + 13631488L;   // [2048(m)][2048(h,d)]
  ushort* wukb  = ws + 17825792L;   // [2048(h,d)][512(c)]
  ushort* wuvb  = ws + 18874368L;   // [2048(h,d)][512(c)]
  ushort* lat   = ws + 19922944L;   // [4096(b,t)][512(c)]
  ushort* qb    = ws + 22020096L;   // [4096(b,s)][2048(h,d)]
  ushort* kb    = ws + 30408704L;   // [4096(b,t)][2048(h,d)]
  ushort* vTb   = ws + 38797312L;   // [2048(h,d)][4096(b,t)]
  ushort* attnO = ws + 47185920L;   // [4096(b,s)][2048(h,d)]

  cvt_kernel<<<8192, 256, 0, stream>>>(x,   xb,   8388608L);
  cvt_kernel<<<1024, 256, 0, stream>>>(Wd,  wdb,  1048576L);
  cvt_kernel<<<4096, 256, 0, stream>>>(Wq,  wqb,  4194304L);
  cvt_kernel<<<4096, 256, 0, stream>>>(Wo,  wob,  4194304L);
  cvt_kernel<<<1024, 256, 0, stream>>>(Wuk, wukb, 1048576L);
  cvt_kernel<<<1024, 256, 0, stream>>>(Wuv, wuvb, 1048576L);

  // latents = x @ Wd^T : [4096, 512]
  gemm_bt<1><<<dim3(4, 32, 1), 256, 0, stream>>>(xb, wdb, lat, 4096, 512, 2048,
      2048, 2048, 512, 0L, 0L, 0L, 1.0f);
  // q = (x @ Wq^T) / sqrt(128) : [4096, 2048]
  gemm_bt<1><<<dim3(16, 32, 1), 256, 0, stream>>>(xb, wqb, qb, 4096, 2048, 2048,
      2048, 2048, 2048, 0L, 0L, 0L, 0.08838834764831845f);
  // k = lat @ Wuk^T : [4096, 2048]
  gemm_bt<1><<<dim3(16, 32, 1), 256, 0, stream>>>(lat, wukb, kb, 4096, 2048, 512,
      512, 512, 2048, 0L, 0L, 0L, 1.0f);
  // vT = Wuv @ lat^T : [2048(h,d)][4096(b,t)]
  gemm_bt<1><<<dim3(32, 16, 1), 256, 0, stream>>>(wuvb, lat, vTb, 2048, 4096, 512,
      512, 512, 4096, 0L, 0L, 0L, 1.0f);
  // flash attention (causal, d=128): attnO [4096][2048]
  flash4_kernel<<<256, 256, 0, stream>>>(qb, kb, vTb, attnO);
  // out = attnO @ Wo^T : fp32 [4096, 2048]
  gemm_bt<0><<<dim3(16, 32, 1), 256, 0, stream>>>(attnO, wob, out, 4096, 2048, 2048,
      2048, 2048, 2048, 0L, 0L, 0L, 1.0f);
}

// Round 5
// 282.302 us; speedup vs baseline: 8.1854x; 1.0032x over previous
//
#include <hip/hip_runtime.h>
#include <hip/hip_bf16.h>

typedef __attribute__((ext_vector_type(8))) short short8x;   // 8 x bf16 (4 VGPR) MFMA A/B frag
typedef __attribute__((ext_vector_type(4))) float f32x4;     // MFMA C/D frag

__device__ __forceinline__ ushort f2bf(float f){
  union { __hip_bfloat16 b; ushort u; } cvt;
  cvt.b = __float2bfloat16(f);                // RNE; compiler can pair into v_cvt_pk_bf16_f32
  return cvt.u;
}

// ---------------- elementwise fp32 -> bf16 ----------------
__global__ __launch_bounds__(256) void cvt_kernel(const float* __restrict__ in, ushort* __restrict__ out, long n){
  long i = ((long)blockIdx.x * 256 + threadIdx.x) * 4;
  if (i >= n) return;
  float4 v = *(const float4*)(in + i);
  ushort4 o;
  o.x = f2bf(v.x); o.y = f2bf(v.y); o.z = f2bf(v.z); o.w = f2bf(v.w);
  *(ushort4*)(out + i) = o;
}

// ---------------- generic bf16 GEMM: C = A[M,K] * B  with B given as BT[N,K] ----------------
// 128x128 tile, BK=32, 4 waves (2x2), double-buffered LDS staged via global_load_lds(16B).
// XCD-aware block swizzle (T1): all launches have (gridDim.x*gridDim.y) % 8 == 0.
template<int OUTBF>
__global__ __launch_bounds__(256, 3)
void gemm_bt(const ushort* __restrict__ A, const ushort* __restrict__ BT, void* __restrict__ Cv,
             int M, int N, int K, int lda, int ldb, int ldc,
             long aZ, long bZ, long cZ, float scale)
{
  __shared__ __align__(16) ushort As[2][128 * 32];
  __shared__ __align__(16) ushort Bs[2][128 * 32];
  const int z = blockIdx.z;
  const ushort* Ab = A + (long)z * aZ;
  const ushort* Bb = BT + (long)z * bZ;
  const int tid = threadIdx.x, lane = tid & 63, w = tid >> 6;
  const int wm = w >> 1, wn = w & 1;
  const int lq = lane & 15, q4 = lane >> 4;

  int lin = blockIdx.x + gridDim.x * blockIdx.y;
  const int cpx = (gridDim.x * gridDim.y) >> 3;
  lin = (lin & 7) * cpx + (lin >> 3);
  const int bx = lin % gridDim.x, by = lin / gridDim.x;

  const long arow = (long)by * 128, brow = (long)bx * 128;
  const int lr = lane >> 2, lc = (lane & 3) * 8;

  const f32x4 z4 = {0.f, 0.f, 0.f, 0.f};
  f32x4 acc[4][4];
#pragma unroll
  for (int i = 0; i < 4; i++)
#pragma unroll
    for (int j = 0; j < 4; j++) acc[i][j] = z4;

  auto stage = [&](int buf, int k0){
#pragma unroll
    for (int is = 0; is < 2; ++is){
      const int rb = is * 64 + w * 16;
      const ushort* ga = Ab + (arow + rb + lr) * (long)lda + k0 + lc;
      const ushort* gb = Bb + (brow + rb + lr) * (long)ldb + k0 + lc;
      __builtin_amdgcn_global_load_lds((const __attribute__((address_space(1))) void*)ga,
                                       (__attribute__((address_space(3))) void*)&As[buf][rb * 32], 16, 0, 0);
      __builtin_amdgcn_global_load_lds((const __attribute__((address_space(1))) void*)gb,
                                       (__attribute__((address_space(3))) void*)&Bs[buf][rb * 32], 16, 0, 0);
    }
  };

  const int nk = K >> 5;
  stage(0, 0);
  for (int kt = 0; kt < nk; ++kt){
    __syncthreads();
    if (kt + 1 < nk) stage((kt + 1) & 1, (kt + 1) * 32);
    const int buf = kt & 1;
    short8x a[4], b[4];
#pragma unroll
    for (int i = 0; i < 4; i++){
      a[i] = *(const short8x*)&As[buf][(wm * 64 + i * 16 + lq) * 32 + q4 * 8];
      b[i] = *(const short8x*)&Bs[buf][(wn * 64 + i * 16 + lq) * 32 + q4 * 8];
    }
#pragma unroll
    for (int i = 0; i < 4; i++)
#pragma unroll
      for (int j = 0; j < 4; j++)
        acc[i][j] = __builtin_amdgcn_mfma_f32_16x16x32_bf16(a[i], b[j], acc[i][j], 0, 0, 0);
  }

  const long crowb = arow + wm * 64;
  const long ccolb = brow + wn * 64;
#pragma unroll
  for (int i = 0; i < 4; i++)
#pragma unroll
    for (int j = 0; j < 4; j++)
#pragma unroll
      for (int r = 0; r < 4; r++){
        const long row = crowb + i * 16 + q4 * 4 + r;
        const long col = ccolb + j * 16 + lq;
        const float v = acc[i][j][r] * scale;
        if (OUTBF) ((ushort*)Cv)[(long)z * cZ + row * ldc + col] = f2bf(v);
        else       ((float*)Cv)[(long)z * cZ + row * ldc + col] = v;
      }
}

// ---------------- flash attention v5: d=128, causal, constant-work paired strips ------------
// 256 blocks (one per CU), 4 waves each. XCD-LOCAL mapping: bh = (blk&7)*4 + ((blk>>3)&3),
// S = blk>>5, so all 8 blocks sharing (b,h) have the same blk%8 -> same XCD -> K/V tiles hit
// that XCD's L2 after the leader fetches them (4 bh x 1MB = 4MB working set per XCD).
// Antithetic strip pair {S, 15-S}: staged tiles (4S+4)+(64-4S) = 68 for EVERY block.
// Depth-2 pipeline, counted vmcnt(4); staging addresses hoisted out of the loop.
// K-tile LDS granule^=(row&7) swizzle (pre-swizzled global src + swizzled read).
__global__ __launch_bounds__(256, 1)
void flash5_kernel(const ushort* __restrict__ q, const ushort* __restrict__ k,
                   const ushort* __restrict__ vT, ushort* __restrict__ attnO)
{
  __shared__ __align__(16) ushort Kb[2][32 * 128];   // [t][d] swizzled granules, 8KB each
  __shared__ __align__(16) ushort Vb[2][128 * 32];   // [d][t] linear, 8KB each
  __shared__ __align__(16) ushort Pl[4][32][40];     // per-wave P^T bounce

  const int tid = threadIdx.x, lane = tid & 63, w = tid >> 6;
  const int lq = lane & 15, q4 = lane >> 4;

  const int bh = (blockIdx.x & 7) * 4 + ((blockIdx.x >> 3) & 3);
  const int S  = blockIdx.x >> 5;
  const int b = bh & 1, h = bh >> 1;

  const ushort* kb_ = k + (long)b * 2048 * 2048 + h * 128;        // row t stride 2048 elems
  const ushort* vb_ = vT + (long)h * 128 * 4096 + (long)b * 2048; // row d stride 4096 elems

  // hoisted per-lane staging addresses (t0-independent parts)
  const ushort* kbase[2]; const ushort* vbase[2]; int kofs[2], vofs[2];
#pragma unroll
  for (int is = 0; is < 2; ++is){
    const int ofse = is * 2048 + w * 512;
    const int row = (ofse >> 7) + (lane >> 4);
    const int gsw = (lane & 15) ^ (row & 7);
    kbase[is] = kb_ + (long)row * 2048 + gsw * 8;
    kofs[is] = ofse;
    const int drow = (ofse >> 5) + (lane >> 2);
    vbase[is] = vb_ + (long)drow * 4096 + (lane & 3) * 8;
    vofs[is] = ofse;
  }

  auto stage = [&](int buf, int tt){
    const long t0 = (long)tt * 32;
#pragma unroll
    for (int is = 0; is < 2; ++is){
      __builtin_amdgcn_global_load_lds((const __attribute__((address_space(1))) void*)(kbase[is] + t0 * 2048),
          (__attribute__((address_space(3))) void*)&Kb[buf][kofs[is]], 16, 0, 0);
      __builtin_amdgcn_global_load_lds((const __attribute__((address_space(1))) void*)(vbase[is] + t0),
          (__attribute__((address_space(3))) void*)&Vb[buf][vofs[is]], 16, 0, 0);
    }
  };

  const f32x4 z4 = {0.f, 0.f, 0.f, 0.f};

#pragma unroll 1
  for (int pass = 0; pass < 2; ++pass){
    const int strip = pass ? (15 - S) : S;
    const int nt    = pass ? (64 - 4 * S) : (4 * S + 4);
    const int wdiag = pass ? (60 - 4 * S + w) : (4 * S + w);

    const int qrow0 = strip * 128 + w * 32;
    const long qgbase = (long)b * 2048 + qrow0;

    // Q B-frags (reused all tiles): s = qrow0+si*16+lq, d = ks*32+q4*8+j
    short8x qf[2][4];
#pragma unroll
    for (int si = 0; si < 2; si++){
      const ushort* qp = q + (qgbase + si * 16 + lq) * 2048 + h * 128 + q4 * 8;
#pragma unroll
      for (int ks = 0; ks < 4; ks++) qf[si][ks] = *(const short8x*)(qp + ks * 32);
    }

    f32x4 oacc[8][2];
#pragma unroll
    for (int dt = 0; dt < 8; dt++){ oacc[dt][0] = z4; oacc[dt][1] = z4; }
    float dsum0 = 0.f, dsum1 = 0.f;

    stage(0, 0);
    stage(1, 1);          // nt >= 4 always

#pragma unroll 1
    for (int tt = 0; tt < nt; ++tt){
      if (tt == nt - 1) asm volatile("s_waitcnt vmcnt(0)" ::: "memory");
      else              asm volatile("s_waitcnt vmcnt(4)" ::: "memory");
      __syncthreads();
      const int cur = tt & 1;

      if (tt <= wdiag){
        // K A-frags from swizzled LDS: row r = ti*16+lq, granule (ks*4+q4)^(r&7)
        short8x ak[2][4];
#pragma unroll
        for (int ti = 0; ti < 2; ti++){
          const int r = ti * 16 + lq;
          const int rb = r * 128;
          const int rx = r & 7;
#pragma unroll
          for (int ks = 0; ks < 4; ks++)
            ak[ti][ks] = *(const short8x*)&Kb[cur][rb + (((ks * 4 + q4) ^ rx) * 8)];
        }
        f32x4 st[2][2] = {{z4, z4}, {z4, z4}};
#pragma unroll
        for (int ks = 0; ks < 4; ks++)
#pragma unroll
          for (int ti = 0; ti < 2; ti++)
#pragma unroll
            for (int si = 0; si < 2; si++)
              st[ti][si] = __builtin_amdgcn_mfma_f32_16x16x32_bf16(ak[ti][ks], qf[si][ks], st[ti][si], 0, 0, 0);

        const bool diag = (tt == wdiag);
#pragma unroll
        for (int ti = 0; ti < 2; ti++)
#pragma unroll
          for (int si = 0; si < 2; si++){
            ushort4 pb;
#pragma unroll
            for (int r = 0; r < 4; r++){
              const int tl = ti * 16 + q4 * 4 + r;
              const int sl = si * 16 + lq;
              float p = __expf(st[ti][si][r]);
              if (diag && tl > sl) p = 0.f;
              if (si) dsum1 += p; else dsum0 += p;
              ((ushort*)&pb)[r] = f2bf(p);
            }
            *(ushort4*)&Pl[w][si * 16 + lq][ti * 16 + q4 * 4] = pb;
          }
        asm volatile("s_waitcnt lgkmcnt(0)" ::: "memory");
        __builtin_amdgcn_sched_barrier(0);
        short8x pf0 = *(const short8x*)&Pl[w][lq][q4 * 8];
        short8x pf1 = *(const short8x*)&Pl[w][16 + lq][q4 * 8];
        __builtin_amdgcn_sched_barrier(0);
        // PV: O^T[d][s] += V^T[d][t] * P^T[t][s]; V frag read is contiguous 1KB per dt
#pragma unroll
        for (int dt = 0; dt < 8; dt++){
          const short8x av = *(const short8x*)&Vb[cur][(dt * 16 + lq) * 32 + q4 * 8];
          oacc[dt][0] = __builtin_amdgcn_mfma_f32_16x16x32_bf16(av, pf0, oacc[dt][0], 0, 0, 0);
          oacc[dt][1] = __builtin_amdgcn_mfma_f32_16x16x32_bf16(av, pf1, oacc[dt][1], 0, 0, 0);
        }
      }
      __syncthreads();                        // all reads of buf[cur] complete
      if (tt + 2 < nt) stage(cur, tt + 2);    // overwrite buf[cur] = buf[(tt+2)&1]
    }

    dsum0 += __shfl_xor(dsum0, 16); dsum0 += __shfl_xor(dsum0, 32);
    dsum1 += __shfl_xor(dsum1, 16); dsum1 += __shfl_xor(dsum1, 32);
    const float inv0 = 1.f / dsum0, inv1 = 1.f / dsum1;

#pragma unroll
    for (int dt = 0; dt < 8; dt++)
#pragma unroll
      for (int si = 0; si < 2; si++){
        const float inv = si ? inv1 : inv0;
        ushort4 o;
        o.x = f2bf(oacc[dt][si][0] * inv);
        o.y = f2bf(oacc[dt][si][1] * inv);
        o.z = f2bf(oacc[dt][si][2] * inv);
        o.w = f2bf(oacc[dt][si][3] * inv);
        *(ushort4*)(attnO + (qgbase + si * 16 + lq) * 2048 + h * 128 + dt * 16 + q4 * 4) = o;
      }
  }
}

// ---------------- host launcher ----------------
extern "C" void kernel_launch(void* const* d_in, const int* in_sizes, int n_in,
                              void* d_out, int out_size, void* d_ws, size_t ws_size,
                              hipStream_t stream)
{
  const float* x   = (const float*)d_in[0];
  const float* Wd  = (const float*)d_in[1];
  const float* Wuk = (const float*)d_in[2];
  const float* Wuv = (const float*)d_in[3];
  const float* Wq  = (const float*)d_in[4];
  const float* Wo  = (const float*)d_in[5];
  float* out = (float*)d_out;
  ushort* ws = (ushort*)d_ws;

  ushort* xb    = ws + 0L;          // [4096][2048]
  ushort* wdb   = ws + 8388608L;    // [512][2048]
  ushort* wqb   = ws + 9437184L;    // [2048(h,d)][2048(m)]
  ushort* wob   = ws + 13631488L;   // [2048(m)][2048(h,d)]
  ushort* wukb  = ws + 17825792L;   // [2048(h,d)][512(c)]
  ushort* wuvb  = ws + 18874368L;   // [2048(h,d)][512(c)]
  ushort* lat   = ws + 19922944L;   // [4096(b,t)][512(c)]
  ushort* qb    = ws + 22020096L;   // [4096(b,s)][2048(h,d)]
  ushort* kb    = ws + 30408704L;   // [4096(b,t)][2048(h,d)]
  ushort* vTb   = ws + 38797312L;   // [2048(h,d)][4096(b,t)]
  ushort* attnO = ws + 47185920L;   // [4096(b,s)][2048(h,d)]

  cvt_kernel<<<8192, 256, 0, stream>>>(x,   xb,   8388608L);
  cvt_kernel<<<1024, 256, 0, stream>>>(Wd,  wdb,  1048576L);
  cvt_kernel<<<4096, 256, 0, stream>>>(Wq,  wqb,  4194304L);
  cvt_kernel<<<4096, 256, 0, stream>>>(Wo,  wob,  4194304L);
  cvt_kernel<<<1024, 256, 0, stream>>>(Wuk, wukb, 1048576L);
  cvt_kernel<<<1024, 256, 0, stream>>>(Wuv, wuvb, 1048576L);

  // latents = x @ Wd^T : [4096, 512]
  gemm_bt<1><<<dim3(4, 32, 1), 256, 0, stream>>>(xb, wdb, lat, 4096, 512, 2048,
      2048, 2048, 512, 0L, 0L, 0L, 1.0f);
  // q = (x @ Wq^T) / sqrt(128) : [4096, 2048]
  gemm_bt<1><<<dim3(16, 32, 1), 256, 0, stream>>>(xb, wqb, qb, 4096, 2048, 2048,
      2048, 2048, 2048, 0L, 0L, 0L, 0.08838834764831845f);
  // k = lat @ Wuk^T : [4096, 2048]
  gemm_bt<1><<<dim3(16, 32, 1), 256, 0, stream>>>(lat, wukb, kb, 4096, 2048, 512,
      512, 512, 2048, 0L, 0L, 0L, 1.0f);
  // vT = Wuv @ lat^T : [2048(h,d)][4096(b,t)]
  gemm_bt<1><<<dim3(32, 16, 1), 256, 0, stream>>>(wuvb, lat, vTb, 2048, 4096, 512,
      512, 512, 4096, 0L, 0L, 0L, 1.0f);
  // flash attention (causal, d=128): attnO [4096][2048]
  flash5_kernel<<<256, 256, 0, stream>>>(qb, kb, vTb, attnO);
  // out = attnO @ Wo^T : fp32 [4096, 2048]
  gemm_bt<0><<<dim3(16, 32, 1), 256, 0, stream>>>(attnO, wob, out, 4096, 2048, 2048,
      2048, 2048, 2048, 0L, 0L, 0L, 1.0f);
}

// Round 6
// 277.275 us; speedup vs baseline: 8.3338x; 1.0181x over previous
//
#include <hip/hip_runtime.h>
#include <hip/hip_bf16.h>

typedef __attribute__((ext_vector_type(8))) short short8x;   // 8 x bf16 (4 VGPR) MFMA A/B frag
typedef __attribute__((ext_vector_type(4))) float f32x4;     // MFMA C/D frag

__device__ __forceinline__ ushort f2bf(float f){
  union { __hip_bfloat16 b; ushort u; } cvt;
  cvt.b = __float2bfloat16(f);                // RNE; compiler can pair into v_cvt_pk_bf16_f32
  return cvt.u;
}

// ---------------- elementwise fp32 -> bf16 ----------------
__global__ __launch_bounds__(256) void cvt_kernel(const float* __restrict__ in, ushort* __restrict__ out, long n){
  long i = ((long)blockIdx.x * 256 + threadIdx.x) * 4;
  if (i >= n) return;
  float4 v = *(const float4*)(in + i);
  ushort4 o;
  o.x = f2bf(v.x); o.y = f2bf(v.y); o.z = f2bf(v.z); o.w = f2bf(v.w);
  *(ushort4*)(out + i) = o;
}

// ---------------- generic bf16 GEMM: C = A[M,K] * B  with B given as BT[N,K] ----------------
// 128x128 tile, BK=32, 4 waves (2x2), double-buffered LDS staged via global_load_lds(16B).
// XCD-aware block swizzle (T1): all launches have (gridDim.x*gridDim.y) % 8 == 0.
template<int OUTBF>
__global__ __launch_bounds__(256, 3)
void gemm_bt(const ushort* __restrict__ A, const ushort* __restrict__ BT, void* __restrict__ Cv,
             int M, int N, int K, int lda, int ldb, int ldc,
             long aZ, long bZ, long cZ, float scale)
{
  __shared__ __align__(16) ushort As[2][128 * 32];
  __shared__ __align__(16) ushort Bs[2][128 * 32];
  const int z = blockIdx.z;
  const ushort* Ab = A + (long)z * aZ;
  const ushort* Bb = BT + (long)z * bZ;
  const int tid = threadIdx.x, lane = tid & 63, w = tid >> 6;
  const int wm = w >> 1, wn = w & 1;
  const int lq = lane & 15, q4 = lane >> 4;

  int lin = blockIdx.x + gridDim.x * blockIdx.y;
  const int cpx = (gridDim.x * gridDim.y) >> 3;
  lin = (lin & 7) * cpx + (lin >> 3);
  const int bx = lin % gridDim.x, by = lin / gridDim.x;

  const long arow = (long)by * 128, brow = (long)bx * 128;
  const int lr = lane >> 2, lc = (lane & 3) * 8;

  const f32x4 z4 = {0.f, 0.f, 0.f, 0.f};
  f32x4 acc[4][4];
#pragma unroll
  for (int i = 0; i < 4; i++)
#pragma unroll
    for (int j = 0; j < 4; j++) acc[i][j] = z4;

  auto stage = [&](int buf, int k0){
#pragma unroll
    for (int is = 0; is < 2; ++is){
      const int rb = is * 64 + w * 16;
      const ushort* ga = Ab + (arow + rb + lr) * (long)lda + k0 + lc;
      const ushort* gb = Bb + (brow + rb + lr) * (long)ldb + k0 + lc;
      __builtin_amdgcn_global_load_lds((const __attribute__((address_space(1))) void*)ga,
                                       (__attribute__((address_space(3))) void*)&As[buf][rb * 32], 16, 0, 0);
      __builtin_amdgcn_global_load_lds((const __attribute__((address_space(1))) void*)gb,
                                       (__attribute__((address_space(3))) void*)&Bs[buf][rb * 32], 16, 0, 0);
    }
  };

  const int nk = K >> 5;
  stage(0, 0);
  for (int kt = 0; kt < nk; ++kt){
    __syncthreads();
    if (kt + 1 < nk) stage((kt + 1) & 1, (kt + 1) * 32);
    const int buf = kt & 1;
    short8x a[4], b[4];
#pragma unroll
    for (int i = 0; i < 4; i++){
      a[i] = *(const short8x*)&As[buf][(wm * 64 + i * 16 + lq) * 32 + q4 * 8];
      b[i] = *(const short8x*)&Bs[buf][(wn * 64 + i * 16 + lq) * 32 + q4 * 8];
    }
#pragma unroll
    for (int i = 0; i < 4; i++)
#pragma unroll
      for (int j = 0; j < 4; j++)
        acc[i][j] = __builtin_amdgcn_mfma_f32_16x16x32_bf16(a[i], b[j], acc[i][j], 0, 0, 0);
  }

  const long crowb = arow + wm * 64;
  const long ccolb = brow + wn * 64;
#pragma unroll
  for (int i = 0; i < 4; i++)
#pragma unroll
    for (int j = 0; j < 4; j++)
#pragma unroll
      for (int r = 0; r < 4; r++){
        const long row = crowb + i * 16 + q4 * 4 + r;
        const long col = ccolb + j * 16 + lq;
        const float v = acc[i][j][r] * scale;
        if (OUTBF) ((ushort*)Cv)[(long)z * cZ + row * ldc + col] = f2bf(v);
        else       ((float*)Cv)[(long)z * cZ + row * ldc + col] = v;
      }
}

// ---------------- flash attention v6: d=128, causal, 512 one-strip blocks, 2 blocks/CU ------
// Block -> (xcd = blk&7, g = blk>>3): bh = xcd*4 + (g&3), strip = 15 - (g>>2).
//  * all blocks of one (b,h) share blk&7 -> same XCD -> K/V stay in that XCD's L2 (round-5
//    verified: FETCH 146->24.6 MB).
//  * heavy strips (more tiles) get LOW blockIdx -> HW dispatches them first; light strips
//    backfill as slots free (LPT). 512 blocks / 256 CUs = 2 co-resident -> stalls of one
//    block hide under the other's MFMA/VALU (m114 co-schedule).
// Depth-2 pipeline, counted vmcnt(4); K-tile granule^=(row&7) swizzle; per-wave P^T bounce.
__global__ __launch_bounds__(256, 1)
void flash6_kernel(const ushort* __restrict__ q, const ushort* __restrict__ k,
                   const ushort* __restrict__ vT, ushort* __restrict__ attnO)
{
  __shared__ __align__(16) ushort Kb[2][32 * 128];   // [t][d] swizzled granules, 8KB each
  __shared__ __align__(16) ushort Vb[2][128 * 32];   // [d][t] linear, 8KB each
  __shared__ __align__(16) ushort Pl[4][32][40];     // per-wave P^T bounce

  const int tid = threadIdx.x, lane = tid & 63, w = tid >> 6;
  const int lq = lane & 15, q4 = lane >> 4;

  const int xcd = blockIdx.x & 7, g = blockIdx.x >> 3;
  const int bh = xcd * 4 + (g & 3);
  const int strip = 15 - (g >> 2);
  const int b = bh & 1, h = bh >> 1;

  const int nt = 4 * strip + 4;
  const int wdiag = 4 * strip + w;

  const ushort* kb_ = k + (long)b * 2048 * 2048 + h * 128;        // row t stride 2048 elems
  const ushort* vb_ = vT + (long)h * 128 * 4096 + (long)b * 2048; // row d stride 4096 elems

  // hoisted per-lane staging addresses (t0-independent parts)
  const ushort* kbase[2]; const ushort* vbase[2]; int kofs[2], vofs[2];
#pragma unroll
  for (int is = 0; is < 2; ++is){
    const int ofse = is * 2048 + w * 512;
    const int row = (ofse >> 7) + (lane >> 4);
    const int gsw = (lane & 15) ^ (row & 7);
    kbase[is] = kb_ + (long)row * 2048 + gsw * 8;
    kofs[is] = ofse;
    const int drow = (ofse >> 5) + (lane >> 2);
    vbase[is] = vb_ + (long)drow * 4096 + (lane & 3) * 8;
    vofs[is] = ofse;
  }

  auto stage = [&](int buf, int tt){
    const long t0 = (long)tt * 32;
#pragma unroll
    for (int is = 0; is < 2; ++is){
      __builtin_amdgcn_global_load_lds((const __attribute__((address_space(1))) void*)(kbase[is] + t0 * 2048),
          (__attribute__((address_space(3))) void*)&Kb[buf][kofs[is]], 16, 0, 0);
      __builtin_amdgcn_global_load_lds((const __attribute__((address_space(1))) void*)(vbase[is] + t0),
          (__attribute__((address_space(3))) void*)&Vb[buf][vofs[is]], 16, 0, 0);
    }
  };

  const f32x4 z4 = {0.f, 0.f, 0.f, 0.f};

  const int qrow0 = strip * 128 + w * 32;
  const long qgbase = (long)b * 2048 + qrow0;

  // Q B-frags (reused all tiles): s = qrow0+si*16+lq, d = ks*32+q4*8+j
  short8x qf[2][4];
#pragma unroll
  for (int si = 0; si < 2; si++){
    const ushort* qp = q + (qgbase + si * 16 + lq) * 2048 + h * 128 + q4 * 8;
#pragma unroll
    for (int ks = 0; ks < 4; ks++) qf[si][ks] = *(const short8x*)(qp + ks * 32);
  }

  f32x4 oacc[8][2];
#pragma unroll
  for (int dt = 0; dt < 8; dt++){ oacc[dt][0] = z4; oacc[dt][1] = z4; }
  float dsum0 = 0.f, dsum1 = 0.f;

  stage(0, 0);
  stage(1, 1);          // nt >= 4 always

#pragma unroll 1
  for (int tt = 0; tt < nt; ++tt){
    if (tt == nt - 1) asm volatile("s_waitcnt vmcnt(0)" ::: "memory");
    else              asm volatile("s_waitcnt vmcnt(4)" ::: "memory");
    __syncthreads();
    const int cur = tt & 1;

    if (tt <= wdiag){
      // K A-frags from swizzled LDS: row r = ti*16+lq, granule (ks*4+q4)^(r&7)
      short8x ak[2][4];
#pragma unroll
      for (int ti = 0; ti < 2; ti++){
        const int r = ti * 16 + lq;
        const int rb = r * 128;
        const int rx = r & 7;
#pragma unroll
        for (int ks = 0; ks < 4; ks++)
          ak[ti][ks] = *(const short8x*)&Kb[cur][rb + (((ks * 4 + q4) ^ rx) * 8)];
      }
      f32x4 st[2][2] = {{z4, z4}, {z4, z4}};
#pragma unroll
      for (int ks = 0; ks < 4; ks++)
#pragma unroll
        for (int ti = 0; ti < 2; ti++)
#pragma unroll
          for (int si = 0; si < 2; si++)
            st[ti][si] = __builtin_amdgcn_mfma_f32_16x16x32_bf16(ak[ti][ks], qf[si][ks], st[ti][si], 0, 0, 0);

      const bool diag = (tt == wdiag);
#pragma unroll
      for (int ti = 0; ti < 2; ti++)
#pragma unroll
        for (int si = 0; si < 2; si++){
          ushort4 pb;
#pragma unroll
          for (int r = 0; r < 4; r++){
            const int tl = ti * 16 + q4 * 4 + r;
            const int sl = si * 16 + lq;
            float p = __expf(st[ti][si][r]);
            if (diag && tl > sl) p = 0.f;
            if (si) dsum1 += p; else dsum0 += p;
            ((ushort*)&pb)[r] = f2bf(p);
          }
          *(ushort4*)&Pl[w][si * 16 + lq][ti * 16 + q4 * 4] = pb;
        }
      asm volatile("s_waitcnt lgkmcnt(0)" ::: "memory");
      __builtin_amdgcn_sched_barrier(0);
      short8x pf0 = *(const short8x*)&Pl[w][lq][q4 * 8];
      short8x pf1 = *(const short8x*)&Pl[w][16 + lq][q4 * 8];
      __builtin_amdgcn_sched_barrier(0);
      // PV: O^T[d][s] += V^T[d][t] * P^T[t][s]; V frag read is contiguous 1KB per dt
#pragma unroll
      for (int dt = 0; dt < 8; dt++){
        const short8x av = *(const short8x*)&Vb[cur][(dt * 16 + lq) * 32 + q4 * 8];
        oacc[dt][0] = __builtin_amdgcn_mfma_f32_16x16x32_bf16(av, pf0, oacc[dt][0], 0, 0, 0);
        oacc[dt][1] = __builtin_amdgcn_mfma_f32_16x16x32_bf16(av, pf1, oacc[dt][1], 0, 0, 0);
      }
    }
    __syncthreads();                        // all reads of buf[cur] complete
    if (tt + 2 < nt) stage(cur, tt + 2);    // overwrite buf[cur] = buf[(tt+2)&1]
  }

  dsum0 += __shfl_xor(dsum0, 16); dsum0 += __shfl_xor(dsum0, 32);
  dsum1 += __shfl_xor(dsum1, 16); dsum1 += __shfl_xor(dsum1, 32);
  const float inv0 = 1.f / dsum0, inv1 = 1.f / dsum1;

#pragma unroll
  for (int dt = 0; dt < 8; dt++)
#pragma unroll
    for (int si = 0; si < 2; si++){
      const float inv = si ? inv1 : inv0;
      ushort4 o;
      o.x = f2bf(oacc[dt][si][0] * inv);
      o.y = f2bf(oacc[dt][si][1] * inv);
      o.z = f2bf(oacc[dt][si][2] * inv);
      o.w = f2bf(oacc[dt][si][3] * inv);
      *(ushort4*)(attnO + (qgbase + si * 16 + lq) * 2048 + h * 128 + dt * 16 + q4 * 4) = o;
    }
}

// ---------------- host launcher ----------------
extern "C" void kernel_launch(void* const* d_in, const int* in_sizes, int n_in,
                              void* d_out, int out_size, void* d_ws, size_t ws_size,
                              hipStream_t stream)
{
  const float* x   = (const float*)d_in[0];
  const float* Wd  = (const float*)d_in[1];
  const float* Wuk = (const float*)d_in[2];
  const float* Wuv = (const float*)d_in[3];
  const float* Wq  = (const float*)d_in[4];
  const float* Wo  = (const float*)d_in[5];
  float* out = (float*)d_out;
  ushort* ws = (ushort*)d_ws;

  ushort* xb    = ws + 0L;          // [4096][2048]
  ushort* wdb   = ws + 8388608L;    // [512][2048]
  ushort* wqb   = ws + 9437184L;    // [2048(h,d)][2048(m)]
  ushort* wob   = ws + 13631488L;   // [2048(m)][2048(h,d)]
  ushort* wukb  = ws + 17825792L;   // [2048(h,d)][512(c)]
  ushort* wuvb  = ws + 18874368L;   // [2048(h,d)][512(c)]
  ushort* lat   = ws + 19922944L;   // [4096(b,t)][512(c)]
  ushort* qb    = ws + 22020096L;   // [4096(b,s)][2048(h,d)]
  ushort* kb    = ws + 30408704L;   // [4096(b,t)][2048(h,d)]
  ushort* vTb   = ws + 38797312L;   // [2048(h,d)][4096(b,t)]
  ushort* attnO = ws + 47185920L;   // [4096(b,s)][2048(h,d)]

  cvt_kernel<<<8192, 256, 0, stream>>>(x,   xb,   8388608L);
  cvt_kernel<<<1024, 256, 0, stream>>>(Wd,  wdb,  1048576L);
  cvt_kernel<<<4096, 256, 0, stream>>>(Wq,  wqb,  4194304L);
  cvt_kernel<<<4096, 256, 0, stream>>>(Wo,  wob,  4194304L);
  cvt_kernel<<<1024, 256, 0, stream>>>(Wuk, wukb, 1048576L);
  cvt_kernel<<<1024, 256, 0, stream>>>(Wuv, wuvb, 1048576L);

  // latents = x @ Wd^T : [4096, 512]
  gemm_bt<1><<<dim3(4, 32, 1), 256, 0, stream>>>(xb, wdb, lat, 4096, 512, 2048,
      2048, 2048, 512, 0L, 0L, 0L, 1.0f);
  // q = (x @ Wq^T) / sqrt(128) : [4096, 2048]
  gemm_bt<1><<<dim3(16, 32, 1), 256, 0, stream>>>(xb, wqb, qb, 4096, 2048, 2048,
      2048, 2048, 2048, 0L, 0L, 0L, 0.08838834764831845f);
  // k = lat @ Wuk^T : [4096, 2048]
  gemm_bt<1><<<dim3(16, 32, 1), 256, 0, stream>>>(lat, wukb, kb, 4096, 2048, 512,
      512, 512, 2048, 0L, 0L, 0L, 1.0f);
  // vT = Wuv @ lat^T : [2048(h,d)][4096(b,t)]
  gemm_bt<1><<<dim3(32, 16, 1), 256, 0, stream>>>(wuvb, lat, vTb, 2048, 4096, 512,
      512, 512, 4096, 0L, 0L, 0L, 1.0f);
  // flash attention (causal, d=128): attnO [4096][2048]
  flash6_kernel<<<512, 256, 0, stream>>>(qb, kb, vTb, attnO);
  // out = attnO @ Wo^T : fp32 [4096, 2048]
  gemm_bt<0><<<dim3(16, 32, 1), 256, 0, stream>>>(attnO, wob, out, 4096, 2048, 2048,
      2048, 2048, 2048, 0L, 0L, 0L, 1.0f);
}